// Round 7
// baseline (88.407 us; speedup 1.0000x reference)
//
#include <hip/hip_runtime.h>

typedef float f32x4 __attribute__((ext_vector_type(4)));
typedef float f32x16 __attribute__((ext_vector_type(16)));
typedef unsigned int u32x4 __attribute__((ext_vector_type(4)));
typedef __bf16 bf16x8 __attribute__((ext_vector_type(8)));
typedef unsigned short ushort_t;

#define NEG2 (-144269.5f)   /* -1e5 * log2(e) */
#define SCLQ (0.18033688f)  /* 0.125 * log2(e) */

constexpr int Ss = 2048, Ee = 1024, Hh = 64;

static __device__ __forceinline__ ushort_t f2bfu(float f) {
  return __builtin_bit_cast(ushort_t, (__bf16)f);
}
static __device__ __forceinline__ f32x4 mfma16(bf16x8 a, bf16x8 b, f32x4 c) {
  return __builtin_amdgcn_mfma_f32_16x16x32_bf16(a, b, c, 0, 0, 0);
}
static __device__ __forceinline__ f32x16 mfma32(bf16x8 a, bf16x8 b, f32x16 c) {
  return __builtin_amdgcn_mfma_f32_32x32x16_bf16(a, b, c, 0, 0, 0);
}
static __device__ __forceinline__ unsigned cvtpk(float a, float b) {
  unsigned r;
  asm("v_cvt_pk_bf16_f32 %0, %1, %2" : "=v"(r) : "v"(a), "v"(b));
  return r;
}
// NOTE: only call with a,b holding DIFFERENT values (R3 bug: identical values
// tie to one phys reg -> in-place self-swap).
static __device__ __forceinline__ void swap32(unsigned& a, unsigned& b) {
  asm("v_permlane32_swap_b32 %0, %1" : "+v"(a), "+v"(b));
}

// ---------------- weight transpose + bf16 convert: Wt[m][h][e] ----------------
__global__ __launch_bounds__(256) void k_wtrans(const float* __restrict__ Wq,
                                                const float* __restrict__ Wk,
                                                const float* __restrict__ Wv,
                                                ushort_t* __restrict__ Wt) {
  __shared__ float tile[64][65];
  const float* W = (blockIdx.y == 0) ? Wq : (blockIdx.y == 1 ? Wk : Wv);
  int kt = blockIdx.x, t = threadIdx.x;
  int r = t >> 2, cq = t & 3;
  const float* src = W + (kt * 64 + r) * Hh + cq * 16;
#pragma unroll
  for (int j = 0; j < 16; j += 4) {
    float4 v = *reinterpret_cast<const float4*>(src + j);
    tile[r][cq * 16 + j + 0] = v.x;
    tile[r][cq * 16 + j + 1] = v.y;
    tile[r][cq * 16 + j + 2] = v.z;
    tile[r][cq * 16 + j + 3] = v.w;
  }
  __syncthreads();
  int n = t >> 2, kq = t & 3;
  ushort_t ob[16];
#pragma unroll
  for (int j = 0; j < 16; ++j) ob[j] = f2bfu(tile[kq * 16 + j][n]);
  ushort_t* dst = Wt + ((size_t)blockIdx.y * 64 + n) * Ee + kt * 64 + kq * 16;
  reinterpret_cast<uint4*>(dst)[0] = reinterpret_cast<uint4*>(ob)[0];
  reinterpret_cast<uint4*>(dst)[1] = reinterpret_cast<uint4*>(ob)[1];
}

// ---------------- fused QKV projection: LDS-staged, double-buffered ----------------
// (unchanged from R6 — proven: fell out of top-5)
__global__ __launch_bounds__(512, 4) void k_proj(const float* __restrict__ hs,
                                                 const float* __restrict__ bq,
                                                 const float* __restrict__ bk,
                                                 const float* __restrict__ bv,
                                                 const ushort_t* __restrict__ Wt,
                                                 const int* __restrict__ am,
                                                 ushort_t* __restrict__ q,
                                                 ushort_t* __restrict__ k,
                                                 ushort_t* __restrict__ vt,
                                                 float* __restrict__ pen) {
  __shared__ __align__(16) ushort_t bufA[2][64][72];   // 18 KB
  __shared__ __align__(16) ushort_t bufW[2][192][72];  // 54 KB

  int t = threadIdx.x, w = t >> 6, l = t & 63, g = l >> 4, c = l & 15;
  int wm = w >> 1, wn = w & 1;
  int row0 = blockIdx.x * 64;

  int ar = t >> 3, ach = t & 7;
  const float* agp = hs + (size_t)(row0 + ar) * Ee + ach * 8;
  const ushort_t* wgp = Wt + (size_t)(t >> 3) * Ee + (t & 7) * 8;

  f32x4 acc[6];
#pragma unroll
  for (int nt = 0; nt < 6; ++nt) acc[nt] = f32x4{0.f, 0.f, 0.f, 0.f};

  float4 aR0, aR1;
  u32x4 wR[3];

  auto LOAD = [&](int kk) {
    aR0 = *reinterpret_cast<const float4*>(agp + kk);
    aR1 = *reinterpret_cast<const float4*>(agp + kk + 4);
#pragma unroll
    for (int j = 0; j < 3; ++j)
      wR[j] = *reinterpret_cast<const u32x4*>(wgp + (size_t)j * 64 * Ee + kk);
  };
  auto WRITE = [&](int buf) {
    bf16x8 av;
    av[0] = (__bf16)aR0.x; av[1] = (__bf16)aR0.y; av[2] = (__bf16)aR0.z; av[3] = (__bf16)aR0.w;
    av[4] = (__bf16)aR1.x; av[5] = (__bf16)aR1.y; av[6] = (__bf16)aR1.z; av[7] = (__bf16)aR1.w;
    *reinterpret_cast<bf16x8*>(&bufA[buf][ar][ach * 8]) = av;
#pragma unroll
    for (int j = 0; j < 3; ++j)
      *reinterpret_cast<u32x4*>(&bufW[buf][(t >> 3) + j * 64][(t & 7) * 8]) = wR[j];
  };
  auto COMPUTE = [&](int buf) {
    const ushort_t* Ab = &bufA[buf][wm * 16 + c][0];
    bf16x8 af0 = *reinterpret_cast<const bf16x8*>(Ab + g * 8);
    bf16x8 af1 = *reinterpret_cast<const bf16x8*>(Ab + 32 + g * 8);
#pragma unroll
    for (int nt = 0; nt < 6; ++nt) {
      const ushort_t* Wb = &bufW[buf][wn * 96 + nt * 16 + c][0];
      bf16x8 b0 = *reinterpret_cast<const bf16x8*>(Wb + g * 8);
      bf16x8 b1 = *reinterpret_cast<const bf16x8*>(Wb + 32 + g * 8);
      acc[nt] = mfma16(af0, b0, acc[nt]);
      acc[nt] = mfma16(af1, b1, acc[nt]);
    }
  };

  LOAD(0);
  WRITE(0);
  __syncthreads();

  int cur = 0;
  for (int s = 0; s < 16; ++s) {
    if (s < 15) LOAD((s + 1) * 64);
    COMPUTE(cur);
    if (s < 15) {
      __syncthreads();
      WRITE(cur ^ 1);
      __syncthreads();
      cur ^= 1;
    }
  }

#pragma unroll
  for (int nt = 0; nt < 6; ++nt) {
    int T = wn * 6 + nt;
    int m = T >> 2;
    int h = (T & 3) * 16 + c;
    const float* bias = (m == 0) ? bq : ((m == 1) ? bk : bv);
    float bb = bias[h];
#pragma unroll
    for (int i = 0; i < 4; ++i) {
      int row = row0 + wm * 16 + g * 4 + i;
      float val = acc[nt][i] + bb;
      if (m == 0) {
        q[(size_t)row * Hh + h] = f2bfu(val * SCLQ);
      } else if (m == 1) {
        k[(size_t)row * Hh + h] = f2bfu(val);
      } else {
        int bi = row >> 11, s2 = row & 2047;
        vt[((size_t)(bi * 64 + h)) * Ss + s2] = f2bfu(val);
      }
    }
  }

  if (t < 64) {
    int grow = row0 + t;
    int bi = grow >> 11, s2 = grow & 2047;
    int mv = am[grow];
    pen[((size_t)bi * 2 + 0) * Ss + s2] = mv ? 0.f : NEG2;
    pen[((size_t)bi * 2 + 1) * Ss + s2] = mv ? NEG2 : 0.f;
  }
}

// ---------------- fused masked flash attention ----------------
// 1-D grid of 512; b = bid&7 (batch-per-XCD: round-robin dispatch pins all of a
// batch's q-tiles to one XCD -> K/V L2-resident), qt = bid>>3.
// 512 threads / 8 waves; wave w owns keys [w*256, w*256+256) (8 tiles of 32).
// Swapped-QK 32x32, lane owns one q-row; FIXED m=0 softmax (scores in exp2
// domain bounded ~2^9 << f32 range; masked -> exp2(-1.4e5) = 0 exactly) -> no
// max tree, no rescale, combine = plain sums.
__global__ __launch_bounds__(512, 4) void k_attn(const ushort_t* __restrict__ qs,
                                                 const ushort_t* __restrict__ km,
                                                 const ushort_t* __restrict__ vt,
                                                 const int* __restrict__ am,
                                                 const float* __restrict__ pen,
                                                 float* __restrict__ out) {
  __shared__ float obuf[8][32][68];
  __shared__ float lls[8][32];

  int t = threadIdx.x, w = t >> 6, l = t & 63, lo = l & 31, hi = l >> 5;
  int bid = blockIdx.x;
  int b = bid & 7, q0 = (bid >> 3) * 32;

  // Q B-frags (hoisted): lane holds Q[q0+lo][c*16 + hi*8 + j]
  const ushort_t* qp = qs + ((size_t)(b * Ss + q0 + lo)) * Hh + hi * 8;
  bf16x8 qf[4];
#pragma unroll
  for (int c = 0; c < 4; ++c) qf[c] = *reinterpret_cast<const bf16x8*>(qp + c * 16);

  int mq = am[b * Ss + q0 + lo];
  float negq = mq ? NEG2 : 0.f;
  const float* psel = pen + ((size_t)b * 2 + (mq ? 0 : 1)) * Ss;

  float ll = 0.f;
  f32x16 o0 = {0.f, 0.f, 0.f, 0.f, 0.f, 0.f, 0.f, 0.f, 0.f, 0.f, 0.f, 0.f, 0.f, 0.f, 0.f, 0.f};
  f32x16 o1 = o0;
  const f32x16 z16 = o0;

  const int kvbeg = w * 256;
  for (int it = 0; it < 8; ++it) {
    int kv0 = kvbeg + it * 32;

    // K A-frags: lane holds K[kv0+lo][c*16 + hi*8 + j]
    const ushort_t* kp = km + ((size_t)(b * Ss + kv0 + lo)) * Hh + hi * 8;
    bf16x8 kf0 = *reinterpret_cast<const bf16x8*>(kp);
    bf16x8 kf1 = *reinterpret_cast<const bf16x8*>(kp + 16);
    bf16x8 kf2 = *reinterpret_cast<const bf16x8*>(kp + 32);
    bf16x8 kf3 = *reinterpret_cast<const bf16x8*>(kp + 48);

    // V B-frags from vt[b][d][s]
    const ushort_t* vp0 = vt + ((size_t)(b * 64 + lo)) * Ss + kv0 + hi * 8;
    const ushort_t* vp1 = vt + ((size_t)(b * 64 + 32 + lo)) * Ss + kv0 + hi * 8;
    bf16x8 vf00 = *reinterpret_cast<const bf16x8*>(vp0);
    bf16x8 vf10 = *reinterpret_cast<const bf16x8*>(vp0 + 16);
    bf16x8 vf01 = *reinterpret_cast<const bf16x8*>(vp1);
    bf16x8 vf11 = *reinterpret_cast<const bf16x8*>(vp1 + 16);

    // penalty vectors: reg r -> key kv0 + (r&3) + 8*(r>>2) + 4*hi
    f32x4 pv[4];
#pragma unroll
    for (int j = 0; j < 4; ++j)
      pv[j] = *reinterpret_cast<const f32x4*>(psel + kv0 + j * 8 + hi * 4);

    // ---- scores: D[key][q], key = (r&3)+8*(r>>2)+4*hi, q = lo ----
    __builtin_amdgcn_s_setprio(1);
    f32x16 sc = mfma32(kf0, qf[0], z16);
    sc = mfma32(kf1, qf[1], sc);
    sc = mfma32(kf2, qf[2], sc);
    sc = mfma32(kf3, qf[3], sc);
    __builtin_amdgcn_s_setprio(0);

    if (kv0 == q0) {  // straddle tile: per-reg causal
#pragma unroll
      for (int r = 0; r < 16; ++r) {
        int kr = (r & 3) + 8 * (r >> 2) + 4 * hi;
        float pc = (kr > lo) ? negq : 0.f;
        sc[r] += pv[r >> 2][r & 3] + pc;
      }
    } else {
      float addt = (kv0 > q0) ? negq : 0.f;
#pragma unroll
      for (int r = 0; r < 16; ++r) sc[r] += pv[r >> 2][r & 3] + addt;
    }

    // ---- p = exp2(sc), row sum (fixed m = 0) ----
    float p[16];
    float ts = 0.f;
#pragma unroll
    for (int r = 0; r < 16; ++r) {
      p[r] = __builtin_amdgcn_exp2f(sc[r]);
      ts += p[r];
    }
    ts += __shfl_xor(ts, 32);
    ll += ts;

    // ---- P -> PV A-frags: 8 cvt_pk + 4 permlane32_swap (distinct values: safe) ----
    unsigned x0 = cvtpk(p[0], p[1]), y0 = cvtpk(p[2], p[3]);
    unsigned z0 = cvtpk(p[4], p[5]), w0 = cvtpk(p[6], p[7]);
    swap32(x0, z0);
    swap32(y0, w0);
    unsigned x1 = cvtpk(p[8], p[9]), y1 = cvtpk(p[10], p[11]);
    unsigned z1 = cvtpk(p[12], p[13]), w1 = cvtpk(p[14], p[15]);
    swap32(x1, z1);
    swap32(y1, w1);
    bf16x8 pa0 = __builtin_bit_cast(bf16x8, u32x4{x0, y0, z0, w0});
    bf16x8 pa1 = __builtin_bit_cast(bf16x8, u32x4{x1, y1, z1, w1});

    // ---- PV: D[q][d] ----
    __builtin_amdgcn_s_setprio(1);
    o0 = mfma32(pa0, vf00, o0);
    o0 = mfma32(pa1, vf10, o0);
    o1 = mfma32(pa0, vf01, o1);
    o1 = mfma32(pa1, vf11, o1);
    __builtin_amdgcn_s_setprio(0);
  }

  // ---- stash partials ----
#pragma unroll
  for (int r = 0; r < 16; ++r) {
    int qrow = (r & 3) + 8 * (r >> 2) + 4 * hi;
    obuf[w][qrow][lo] = o0[r];
    obuf[w][qrow][32 + lo] = o1[r];
  }
  if (hi == 0) lls[w][lo] = ll;
  __syncthreads();

  // ---- combine 8 KV-split partials (plain sums): t -> (qr = t>>4, float4 col dg) ----
  int qr = t >> 4, dg = t & 15;
  float lg = 0.f;
#pragma unroll
  for (int ww = 0; ww < 8; ++ww) lg += lls[ww][qr];
  float4 ov = {0.f, 0.f, 0.f, 0.f};
#pragma unroll
  for (int ww = 0; ww < 8; ++ww) {
    float4 cv = *reinterpret_cast<const float4*>(&obuf[ww][qr][dg * 4]);
    ov.x += cv.x; ov.y += cv.y; ov.z += cv.z; ov.w += cv.w;
  }
  float inv = 1.f / lg;
  float4 res = {ov.x * inv, ov.y * inv, ov.z * inv, ov.w * inv};
  *reinterpret_cast<float4*>(out + ((size_t)(b * Ss + q0 + qr)) * Hh + dg * 4) = res;
}

extern "C" void kernel_launch(void* const* d_in, const int* in_sizes, int n_in,
                              void* d_out, int out_size, void* d_ws, size_t ws_size,
                              hipStream_t stream) {
  const float* hs = (const float*)d_in[0];
  const int* am = (const int*)d_in[1];
  const float* Wq = (const float*)d_in[2];
  const float* bq = (const float*)d_in[3];
  const float* Wk = (const float*)d_in[4];
  const float* bk = (const float*)d_in[5];
  const float* Wv = (const float*)d_in[6];
  const float* bv = (const float*)d_in[7];
  float* out = (float*)d_out;

  char* ws = (char*)d_ws;
  ushort_t* qsp = (ushort_t*)(ws + 0);                  // 2 MB: [B*S][64] bf16, scaled
  ushort_t* kp = (ushort_t*)(ws + (2u << 20));          // 2 MB: [B*S][64] bf16
  ushort_t* vtp = (ushort_t*)(ws + (4u << 20));         // 2 MB: [B][64][S] bf16 (V^T)
  ushort_t* wtp = (ushort_t*)(ws + (6u << 20));         // 384 KB: [3][64][1024] bf16 (W^T)
  float* penp = (float*)(ws + (6u << 20) + (512u << 10));  // 128 KB: [B][2][S] f32

  k_wtrans<<<dim3(16, 3), 256, 0, stream>>>(Wq, Wk, Wv, wtp);
  k_proj<<<dim3(256), 512, 0, stream>>>(hs, bq, bk, bv, wtp, am, qsp, kp, vtp, penp);
  k_attn<<<dim3(512), 512, 0, stream>>>(qsp, kp, vtp, am, penp, out);
}

// Round 8
// 72.280 us; speedup vs baseline: 1.2231x; 1.2231x over previous
//
#include <hip/hip_runtime.h>

typedef float f32x4 __attribute__((ext_vector_type(4)));
typedef float f32x16 __attribute__((ext_vector_type(16)));
typedef unsigned int u32x4 __attribute__((ext_vector_type(4)));
typedef __bf16 bf16x8 __attribute__((ext_vector_type(8)));
typedef unsigned short ushort_t;

#define NEG2 (-144269.5f)   /* -1e5 * log2(e) */
#define SCLQ (0.18033688f)  /* 0.125 * log2(e) */

constexpr int Ss = 2048, Ee = 1024, Hh = 64;

static __device__ __forceinline__ ushort_t f2bfu(float f) {
  return __builtin_bit_cast(ushort_t, (__bf16)f);
}
static __device__ __forceinline__ f32x4 mfma16(bf16x8 a, bf16x8 b, f32x4 c) {
  return __builtin_amdgcn_mfma_f32_16x16x32_bf16(a, b, c, 0, 0, 0);
}
static __device__ __forceinline__ f32x16 mfma32(bf16x8 a, bf16x8 b, f32x16 c) {
  return __builtin_amdgcn_mfma_f32_32x32x16_bf16(a, b, c, 0, 0, 0);
}
static __device__ __forceinline__ unsigned cvtpk(float a, float b) {
  unsigned r;
  asm("v_cvt_pk_bf16_f32 %0, %1, %2" : "=v"(r) : "v"(a), "v"(b));
  return r;
}
// NOTE: only call with a,b holding DIFFERENT values (R3 bug: identical values
// tie to one phys reg -> in-place self-swap).
static __device__ __forceinline__ void swap32(unsigned& a, unsigned& b) {
  asm("v_permlane32_swap_b32 %0, %1" : "+v"(a), "+v"(b));
}

// ---------------- weight transpose + bf16 convert: Wt[m][h][e] ----------------
__global__ __launch_bounds__(256) void k_wtrans(const float* __restrict__ Wq,
                                                const float* __restrict__ Wk,
                                                const float* __restrict__ Wv,
                                                ushort_t* __restrict__ Wt) {
  __shared__ float tile[64][65];
  const float* W = (blockIdx.y == 0) ? Wq : (blockIdx.y == 1 ? Wk : Wv);
  int kt = blockIdx.x, t = threadIdx.x;
  int r = t >> 2, cq = t & 3;
  const float* src = W + (kt * 64 + r) * Hh + cq * 16;
#pragma unroll
  for (int j = 0; j < 16; j += 4) {
    float4 v = *reinterpret_cast<const float4*>(src + j);
    tile[r][cq * 16 + j + 0] = v.x;
    tile[r][cq * 16 + j + 1] = v.y;
    tile[r][cq * 16 + j + 2] = v.z;
    tile[r][cq * 16 + j + 3] = v.w;
  }
  __syncthreads();
  int n = t >> 2, kq = t & 3;
  ushort_t ob[16];
#pragma unroll
  for (int j = 0; j < 16; ++j) ob[j] = f2bfu(tile[kq * 16 + j][n]);
  ushort_t* dst = Wt + ((size_t)blockIdx.y * 64 + n) * Ee + kt * 64 + kq * 16;
  reinterpret_cast<uint4*>(dst)[0] = reinterpret_cast<uint4*>(ob)[0];
  reinterpret_cast<uint4*>(dst)[1] = reinterpret_cast<uint4*>(ob)[1];
}

// ---------------- fused QKV projection: LDS-staged, double-buffered ----------------
// (unchanged from R6 — proven: fell out of top-5)
__global__ __launch_bounds__(512, 4) void k_proj(const float* __restrict__ hs,
                                                 const float* __restrict__ bq,
                                                 const float* __restrict__ bk,
                                                 const float* __restrict__ bv,
                                                 const ushort_t* __restrict__ Wt,
                                                 const int* __restrict__ am,
                                                 ushort_t* __restrict__ q,
                                                 ushort_t* __restrict__ k,
                                                 ushort_t* __restrict__ vt,
                                                 float* __restrict__ pen) {
  __shared__ __align__(16) ushort_t bufA[2][64][72];   // 18 KB
  __shared__ __align__(16) ushort_t bufW[2][192][72];  // 54 KB

  int t = threadIdx.x, w = t >> 6, l = t & 63, g = l >> 4, c = l & 15;
  int wm = w >> 1, wn = w & 1;
  int row0 = blockIdx.x * 64;

  int ar = t >> 3, ach = t & 7;
  const float* agp = hs + (size_t)(row0 + ar) * Ee + ach * 8;
  const ushort_t* wgp = Wt + (size_t)(t >> 3) * Ee + (t & 7) * 8;

  f32x4 acc[6];
#pragma unroll
  for (int nt = 0; nt < 6; ++nt) acc[nt] = f32x4{0.f, 0.f, 0.f, 0.f};

  float4 aR0, aR1;
  u32x4 wR[3];

  auto LOAD = [&](int kk) {
    aR0 = *reinterpret_cast<const float4*>(agp + kk);
    aR1 = *reinterpret_cast<const float4*>(agp + kk + 4);
#pragma unroll
    for (int j = 0; j < 3; ++j)
      wR[j] = *reinterpret_cast<const u32x4*>(wgp + (size_t)j * 64 * Ee + kk);
  };
  auto WRITE = [&](int buf) {
    bf16x8 av;
    av[0] = (__bf16)aR0.x; av[1] = (__bf16)aR0.y; av[2] = (__bf16)aR0.z; av[3] = (__bf16)aR0.w;
    av[4] = (__bf16)aR1.x; av[5] = (__bf16)aR1.y; av[6] = (__bf16)aR1.z; av[7] = (__bf16)aR1.w;
    *reinterpret_cast<bf16x8*>(&bufA[buf][ar][ach * 8]) = av;
#pragma unroll
    for (int j = 0; j < 3; ++j)
      *reinterpret_cast<u32x4*>(&bufW[buf][(t >> 3) + j * 64][(t & 7) * 8]) = wR[j];
  };
  auto COMPUTE = [&](int buf) {
    const ushort_t* Ab = &bufA[buf][wm * 16 + c][0];
    bf16x8 af0 = *reinterpret_cast<const bf16x8*>(Ab + g * 8);
    bf16x8 af1 = *reinterpret_cast<const bf16x8*>(Ab + 32 + g * 8);
#pragma unroll
    for (int nt = 0; nt < 6; ++nt) {
      const ushort_t* Wb = &bufW[buf][wn * 96 + nt * 16 + c][0];
      bf16x8 b0 = *reinterpret_cast<const bf16x8*>(Wb + g * 8);
      bf16x8 b1 = *reinterpret_cast<const bf16x8*>(Wb + 32 + g * 8);
      acc[nt] = mfma16(af0, b0, acc[nt]);
      acc[nt] = mfma16(af1, b1, acc[nt]);
    }
  };

  LOAD(0);
  WRITE(0);
  __syncthreads();

  int cur = 0;
  for (int s = 0; s < 16; ++s) {
    if (s < 15) LOAD((s + 1) * 64);
    COMPUTE(cur);
    if (s < 15) {
      __syncthreads();
      WRITE(cur ^ 1);
      __syncthreads();
      cur ^= 1;
    }
  }

#pragma unroll
  for (int nt = 0; nt < 6; ++nt) {
    int T = wn * 6 + nt;
    int m = T >> 2;
    int h = (T & 3) * 16 + c;
    const float* bias = (m == 0) ? bq : ((m == 1) ? bk : bv);
    float bb = bias[h];
#pragma unroll
    for (int i = 0; i < 4; ++i) {
      int row = row0 + wm * 16 + g * 4 + i;
      float val = acc[nt][i] + bb;
      if (m == 0) {
        q[(size_t)row * Hh + h] = f2bfu(val * SCLQ);
      } else if (m == 1) {
        k[(size_t)row * Hh + h] = f2bfu(val);
      } else {
        int bi = row >> 11, s2 = row & 2047;
        vt[((size_t)(bi * 64 + h)) * Ss + s2] = f2bfu(val);
      }
    }
  }

  if (t < 64) {
    int grow = row0 + t;
    int bi = grow >> 11, s2 = grow & 2047;
    int mv = am[grow];
    pen[((size_t)bi * 2 + 0) * Ss + s2] = mv ? 0.f : NEG2;
    pen[((size_t)bi * 2 + 1) * Ss + s2] = mv ? NEG2 : 0.f;
  }
}

// ---------------- fused masked flash attention ----------------
// 1-D grid of 512; b = bid&7 (batch-per-XCD), qt = bid>>3.
// 512 threads / 8 waves; wave w owns keys [w*256, w*256+256) (8 tiles of 32).
// Swapped-QK 32x32, lane owns one q-row; FIXED m=0 softmax -> no max tree,
// no rescale, combine = plain sums.
// launch_bounds(512, 2): VGPR cap 256 -- R7's (512,4) cap=128 made the
// allocator squeeze to 64 VGPR and spill ~25 MB/dispatch to scratch
// (WRITE_SIZE 29.7 MB vs 4 MB output). Natural allocation is ~110-130.
__global__ __launch_bounds__(512, 2) void k_attn(const ushort_t* __restrict__ qs,
                                                 const ushort_t* __restrict__ km,
                                                 const ushort_t* __restrict__ vt,
                                                 const int* __restrict__ am,
                                                 const float* __restrict__ pen,
                                                 float* __restrict__ out) {
  __shared__ float obuf[8][32][68];
  __shared__ float lls[8][32];

  int t = threadIdx.x, w = t >> 6, l = t & 63, lo = l & 31, hi = l >> 5;
  int bid = blockIdx.x;
  int b = bid & 7, q0 = (bid >> 3) * 32;

  // Q B-frags (hoisted): lane holds Q[q0+lo][c*16 + hi*8 + j]
  const ushort_t* qp = qs + ((size_t)(b * Ss + q0 + lo)) * Hh + hi * 8;
  bf16x8 qf[4];
#pragma unroll
  for (int c = 0; c < 4; ++c) qf[c] = *reinterpret_cast<const bf16x8*>(qp + c * 16);

  int mq = am[b * Ss + q0 + lo];
  float negq = mq ? NEG2 : 0.f;
  const float* psel = pen + ((size_t)b * 2 + (mq ? 0 : 1)) * Ss;

  float ll = 0.f;
  f32x16 o0 = {0.f, 0.f, 0.f, 0.f, 0.f, 0.f, 0.f, 0.f, 0.f, 0.f, 0.f, 0.f, 0.f, 0.f, 0.f, 0.f};
  f32x16 o1 = o0;
  const f32x16 z16 = o0;

  const int kvbeg = w * 256;
  for (int it = 0; it < 8; ++it) {
    int kv0 = kvbeg + it * 32;

    // K A-frags: lane holds K[kv0+lo][c*16 + hi*8 + j]
    const ushort_t* kp = km + ((size_t)(b * Ss + kv0 + lo)) * Hh + hi * 8;
    bf16x8 kf0 = *reinterpret_cast<const bf16x8*>(kp);
    bf16x8 kf1 = *reinterpret_cast<const bf16x8*>(kp + 16);
    bf16x8 kf2 = *reinterpret_cast<const bf16x8*>(kp + 32);
    bf16x8 kf3 = *reinterpret_cast<const bf16x8*>(kp + 48);

    // V B-frags from vt[b][d][s]
    const ushort_t* vp0 = vt + ((size_t)(b * 64 + lo)) * Ss + kv0 + hi * 8;
    const ushort_t* vp1 = vt + ((size_t)(b * 64 + 32 + lo)) * Ss + kv0 + hi * 8;
    bf16x8 vf00 = *reinterpret_cast<const bf16x8*>(vp0);
    bf16x8 vf10 = *reinterpret_cast<const bf16x8*>(vp0 + 16);
    bf16x8 vf01 = *reinterpret_cast<const bf16x8*>(vp1);
    bf16x8 vf11 = *reinterpret_cast<const bf16x8*>(vp1 + 16);

    // penalty vectors: reg r -> key kv0 + (r&3) + 8*(r>>2) + 4*hi
    f32x4 pv[4];
#pragma unroll
    for (int j = 0; j < 4; ++j)
      pv[j] = *reinterpret_cast<const f32x4*>(psel + kv0 + j * 8 + hi * 4);

    // ---- scores: D[key][q], key = (r&3)+8*(r>>2)+4*hi, q = lo ----
    __builtin_amdgcn_s_setprio(1);
    f32x16 sc = mfma32(kf0, qf[0], z16);
    sc = mfma32(kf1, qf[1], sc);
    sc = mfma32(kf2, qf[2], sc);
    sc = mfma32(kf3, qf[3], sc);
    __builtin_amdgcn_s_setprio(0);

    if (kv0 == q0) {  // straddle tile: per-reg causal
#pragma unroll
      for (int r = 0; r < 16; ++r) {
        int kr = (r & 3) + 8 * (r >> 2) + 4 * hi;
        float pc = (kr > lo) ? negq : 0.f;
        sc[r] += pv[r >> 2][r & 3] + pc;
      }
    } else {
      float addt = (kv0 > q0) ? negq : 0.f;
#pragma unroll
      for (int r = 0; r < 16; ++r) sc[r] += pv[r >> 2][r & 3] + addt;
    }

    // ---- p = exp2(sc), row sum (fixed m = 0) ----
    float p[16];
    float ts = 0.f;
#pragma unroll
    for (int r = 0; r < 16; ++r) {
      p[r] = __builtin_amdgcn_exp2f(sc[r]);
      ts += p[r];
    }
    ts += __shfl_xor(ts, 32);
    ll += ts;

    // ---- P -> PV A-frags: 8 cvt_pk + 4 permlane32_swap (distinct values: safe) ----
    unsigned x0 = cvtpk(p[0], p[1]), y0 = cvtpk(p[2], p[3]);
    unsigned z0 = cvtpk(p[4], p[5]), w0 = cvtpk(p[6], p[7]);
    swap32(x0, z0);
    swap32(y0, w0);
    unsigned x1 = cvtpk(p[8], p[9]), y1 = cvtpk(p[10], p[11]);
    unsigned z1 = cvtpk(p[12], p[13]), w1 = cvtpk(p[14], p[15]);
    swap32(x1, z1);
    swap32(y1, w1);
    bf16x8 pa0 = __builtin_bit_cast(bf16x8, u32x4{x0, y0, z0, w0});
    bf16x8 pa1 = __builtin_bit_cast(bf16x8, u32x4{x1, y1, z1, w1});

    // ---- PV: D[q][d] ----
    __builtin_amdgcn_s_setprio(1);
    o0 = mfma32(pa0, vf00, o0);
    o0 = mfma32(pa1, vf10, o0);
    o1 = mfma32(pa0, vf01, o1);
    o1 = mfma32(pa1, vf11, o1);
    __builtin_amdgcn_s_setprio(0);
  }

  // ---- stash partials ----
#pragma unroll
  for (int r = 0; r < 16; ++r) {
    int qrow = (r & 3) + 8 * (r >> 2) + 4 * hi;
    obuf[w][qrow][lo] = o0[r];
    obuf[w][qrow][32 + lo] = o1[r];
  }
  if (hi == 0) lls[w][lo] = ll;
  __syncthreads();

  // ---- combine 8 KV-split partials (plain sums): t -> (qr = t>>4, float4 col dg) ----
  int qr = t >> 4, dg = t & 15;
  float lg = 0.f;
#pragma unroll
  for (int ww = 0; ww < 8; ++ww) lg += lls[ww][qr];
  float4 ov = {0.f, 0.f, 0.f, 0.f};
#pragma unroll
  for (int ww = 0; ww < 8; ++ww) {
    float4 cv = *reinterpret_cast<const float4*>(&obuf[ww][qr][dg * 4]);
    ov.x += cv.x; ov.y += cv.y; ov.z += cv.z; ov.w += cv.w;
  }
  float inv = 1.f / lg;
  float4 res = {ov.x * inv, ov.y * inv, ov.z * inv, ov.w * inv};
  *reinterpret_cast<float4*>(out + ((size_t)(b * Ss + q0 + qr)) * Hh + dg * 4) = res;
}

extern "C" void kernel_launch(void* const* d_in, const int* in_sizes, int n_in,
                              void* d_out, int out_size, void* d_ws, size_t ws_size,
                              hipStream_t stream) {
  const float* hs = (const float*)d_in[0];
  const int* am = (const int*)d_in[1];
  const float* Wq = (const float*)d_in[2];
  const float* bq = (const float*)d_in[3];
  const float* Wk = (const float*)d_in[4];
  const float* bk = (const float*)d_in[5];
  const float* Wv = (const float*)d_in[6];
  const float* bv = (const float*)d_in[7];
  float* out = (float*)d_out;

  char* ws = (char*)d_ws;
  ushort_t* qsp = (ushort_t*)(ws + 0);                  // 2 MB: [B*S][64] bf16, scaled
  ushort_t* kp = (ushort_t*)(ws + (2u << 20));          // 2 MB: [B*S][64] bf16
  ushort_t* vtp = (ushort_t*)(ws + (4u << 20));         // 2 MB: [B][64][S] bf16 (V^T)
  ushort_t* wtp = (ushort_t*)(ws + (6u << 20));         // 384 KB: [3][64][1024] bf16 (W^T)
  float* penp = (float*)(ws + (6u << 20) + (512u << 10));  // 128 KB: [B][2][S] f32

  k_wtrans<<<dim3(16, 3), 256, 0, stream>>>(Wq, Wk, Wv, wtp);
  k_proj<<<dim3(256), 512, 0, stream>>>(hs, bq, bk, bv, wtp, am, qsp, kp, vtp, penp);
  k_attn<<<dim3(512), 512, 0, stream>>>(qsp, kp, vtp, am, penp, out);
}

// Round 9
// 71.257 us; speedup vs baseline: 1.2407x; 1.0144x over previous
//
#include <hip/hip_runtime.h>

typedef float f32x4 __attribute__((ext_vector_type(4)));
typedef float f32x16 __attribute__((ext_vector_type(16)));
typedef unsigned int u32x4 __attribute__((ext_vector_type(4)));
typedef __bf16 bf16x8 __attribute__((ext_vector_type(8)));
typedef unsigned short ushort_t;

#define NEG2 (-144269.5f)   /* -1e5 * log2(e) */
#define SCLQ (0.18033688f)  /* 0.125 * log2(e) */

constexpr int Ss = 2048, Ee = 1024, Hh = 64;

static __device__ __forceinline__ ushort_t f2bfu(float f) {
  return __builtin_bit_cast(ushort_t, (__bf16)f);
}
static __device__ __forceinline__ f32x4 mfma16(bf16x8 a, bf16x8 b, f32x4 c) {
  return __builtin_amdgcn_mfma_f32_16x16x32_bf16(a, b, c, 0, 0, 0);
}
static __device__ __forceinline__ f32x16 mfma32(bf16x8 a, bf16x8 b, f32x16 c) {
  return __builtin_amdgcn_mfma_f32_32x32x16_bf16(a, b, c, 0, 0, 0);
}
static __device__ __forceinline__ unsigned cvtpk(float a, float b) {
  unsigned r;
  asm("v_cvt_pk_bf16_f32 %0, %1, %2" : "=v"(r) : "v"(a), "v"(b));
  return r;
}
// NOTE: only call with a,b holding DIFFERENT values (R3 bug: identical values
// tie to one phys reg -> in-place self-swap).
static __device__ __forceinline__ void swap32(unsigned& a, unsigned& b) {
  asm("v_permlane32_swap_b32 %0, %1" : "+v"(a), "+v"(b));
}

// ---------------- weight transpose + bf16 convert: Wt[m][h][e] ----------------
__global__ __launch_bounds__(256) void k_wtrans(const float* __restrict__ Wq,
                                                const float* __restrict__ Wk,
                                                const float* __restrict__ Wv,
                                                ushort_t* __restrict__ Wt) {
  __shared__ float tile[64][65];
  const float* W = (blockIdx.y == 0) ? Wq : (blockIdx.y == 1 ? Wk : Wv);
  int kt = blockIdx.x, t = threadIdx.x;
  int r = t >> 2, cq = t & 3;
  const float* src = W + (kt * 64 + r) * Hh + cq * 16;
#pragma unroll
  for (int j = 0; j < 16; j += 4) {
    float4 v = *reinterpret_cast<const float4*>(src + j);
    tile[r][cq * 16 + j + 0] = v.x;
    tile[r][cq * 16 + j + 1] = v.y;
    tile[r][cq * 16 + j + 2] = v.z;
    tile[r][cq * 16 + j + 3] = v.w;
  }
  __syncthreads();
  int n = t >> 2, kq = t & 3;
  ushort_t ob[16];
#pragma unroll
  for (int j = 0; j < 16; ++j) ob[j] = f2bfu(tile[kq * 16 + j][n]);
  ushort_t* dst = Wt + ((size_t)blockIdx.y * 64 + n) * Ee + kt * 64 + kq * 16;
  reinterpret_cast<uint4*>(dst)[0] = reinterpret_cast<uint4*>(ob)[0];
  reinterpret_cast<uint4*>(dst)[1] = reinterpret_cast<uint4*>(ob)[1];
}

// ---------------- fused QKV projection: LDS-staged, double-buffered ----------------
// (unchanged from R6 — proven)
__global__ __launch_bounds__(512, 4) void k_proj(const float* __restrict__ hs,
                                                 const float* __restrict__ bq,
                                                 const float* __restrict__ bk,
                                                 const float* __restrict__ bv,
                                                 const ushort_t* __restrict__ Wt,
                                                 const int* __restrict__ am,
                                                 ushort_t* __restrict__ q,
                                                 ushort_t* __restrict__ k,
                                                 ushort_t* __restrict__ vt,
                                                 float* __restrict__ pen) {
  __shared__ __align__(16) ushort_t bufA[2][64][72];   // 18 KB
  __shared__ __align__(16) ushort_t bufW[2][192][72];  // 54 KB

  int t = threadIdx.x, w = t >> 6, l = t & 63, g = l >> 4, c = l & 15;
  int wm = w >> 1, wn = w & 1;
  int row0 = blockIdx.x * 64;

  int ar = t >> 3, ach = t & 7;
  const float* agp = hs + (size_t)(row0 + ar) * Ee + ach * 8;
  const ushort_t* wgp = Wt + (size_t)(t >> 3) * Ee + (t & 7) * 8;

  f32x4 acc[6];
#pragma unroll
  for (int nt = 0; nt < 6; ++nt) acc[nt] = f32x4{0.f, 0.f, 0.f, 0.f};

  float4 aR0, aR1;
  u32x4 wR[3];

  auto LOAD = [&](int kk) {
    aR0 = *reinterpret_cast<const float4*>(agp + kk);
    aR1 = *reinterpret_cast<const float4*>(agp + kk + 4);
#pragma unroll
    for (int j = 0; j < 3; ++j)
      wR[j] = *reinterpret_cast<const u32x4*>(wgp + (size_t)j * 64 * Ee + kk);
  };
  auto WRITE = [&](int buf) {
    bf16x8 av;
    av[0] = (__bf16)aR0.x; av[1] = (__bf16)aR0.y; av[2] = (__bf16)aR0.z; av[3] = (__bf16)aR0.w;
    av[4] = (__bf16)aR1.x; av[5] = (__bf16)aR1.y; av[6] = (__bf16)aR1.z; av[7] = (__bf16)aR1.w;
    *reinterpret_cast<bf16x8*>(&bufA[buf][ar][ach * 8]) = av;
#pragma unroll
    for (int j = 0; j < 3; ++j)
      *reinterpret_cast<u32x4*>(&bufW[buf][(t >> 3) + j * 64][(t & 7) * 8]) = wR[j];
  };
  auto COMPUTE = [&](int buf) {
    const ushort_t* Ab = &bufA[buf][wm * 16 + c][0];
    bf16x8 af0 = *reinterpret_cast<const bf16x8*>(Ab + g * 8);
    bf16x8 af1 = *reinterpret_cast<const bf16x8*>(Ab + 32 + g * 8);
#pragma unroll
    for (int nt = 0; nt < 6; ++nt) {
      const ushort_t* Wb = &bufW[buf][wn * 96 + nt * 16 + c][0];
      bf16x8 b0 = *reinterpret_cast<const bf16x8*>(Wb + g * 8);
      bf16x8 b1 = *reinterpret_cast<const bf16x8*>(Wb + 32 + g * 8);
      acc[nt] = mfma16(af0, b0, acc[nt]);
      acc[nt] = mfma16(af1, b1, acc[nt]);
    }
  };

  LOAD(0);
  WRITE(0);
  __syncthreads();

  int cur = 0;
  for (int s = 0; s < 16; ++s) {
    if (s < 15) LOAD((s + 1) * 64);
    COMPUTE(cur);
    if (s < 15) {
      __syncthreads();
      WRITE(cur ^ 1);
      __syncthreads();
      cur ^= 1;
    }
  }

#pragma unroll
  for (int nt = 0; nt < 6; ++nt) {
    int T = wn * 6 + nt;
    int m = T >> 2;
    int h = (T & 3) * 16 + c;
    const float* bias = (m == 0) ? bq : ((m == 1) ? bk : bv);
    float bb = bias[h];
#pragma unroll
    for (int i = 0; i < 4; ++i) {
      int row = row0 + wm * 16 + g * 4 + i;
      float val = acc[nt][i] + bb;
      if (m == 0) {
        q[(size_t)row * Hh + h] = f2bfu(val * SCLQ);
      } else if (m == 1) {
        k[(size_t)row * Hh + h] = f2bfu(val);
      } else {
        int bi = row >> 11, s2 = row & 2047;
        vt[((size_t)(bi * 64 + h)) * Ss + s2] = f2bfu(val);
      }
    }
  }

  if (t < 64) {
    int grow = row0 + t;
    int bi = grow >> 11, s2 = grow & 2047;
    int mv = am[grow];
    pen[((size_t)bi * 2 + 0) * Ss + s2] = mv ? 0.f : NEG2;
    pen[((size_t)bi * 2 + 1) * Ss + s2] = mv ? NEG2 : 0.f;
  }
}

// ---------------- fused masked flash attention, deep-ILP KVBLK=64 ----------------
// grid 512 (b = bid&7 batch-per-XCD, qt = bid>>3); block 256 thr / 4 waves.
// Wave w owns keys [w*512, +512) = 8 iterations x 64 keys (two 32-key subtiles
// A,B). QK_B issues right after QK_A so the MFMA pipe chews B while A's softmax
// runs on VALU; V/pen loads issue a phase early; next iteration's K prefetched
// into registers before B's softmax. Only LDS op in loop: none (ll cross-half
// shfl hoisted out — sum commutes). Registers deliberately in the 129-256 band
// (8 waves/CU): trading TLP for per-wave ILP, HK-style.
__global__ __launch_bounds__(256, 2) void k_attn(const ushort_t* __restrict__ qs,
                                                 const ushort_t* __restrict__ km,
                                                 const ushort_t* __restrict__ vt,
                                                 const int* __restrict__ am,
                                                 const float* __restrict__ pen,
                                                 float* __restrict__ out) {
  __shared__ float obuf[4][32][68];
  __shared__ float lls[4][32];

  int t = threadIdx.x, w = t >> 6, l = t & 63, lo = l & 31, hi = l >> 5;
  int bid = blockIdx.x;
  int b = bid & 7, q0 = (bid >> 3) * 32;

  // Q B-frags (hoisted): lane holds Q[q0+lo][c*16 + hi*8 + j]
  const ushort_t* qp = qs + ((size_t)(b * Ss + q0 + lo)) * Hh + hi * 8;
  bf16x8 qf[4];
#pragma unroll
  for (int c = 0; c < 4; ++c) qf[c] = *reinterpret_cast<const bf16x8*>(qp + c * 16);

  int mq = am[b * Ss + q0 + lo];
  float negq = mq ? NEG2 : 0.f;
  const float* psel = pen + ((size_t)b * 2 + (mq ? 0 : 1)) * Ss;

  float ll = 0.f;
  f32x16 o0 = {0.f, 0.f, 0.f, 0.f, 0.f, 0.f, 0.f, 0.f, 0.f, 0.f, 0.f, 0.f, 0.f, 0.f, 0.f, 0.f};
  f32x16 o1 = o0;
  const f32x16 z16 = o0;

  const int kvbeg = w * 512;
  const ushort_t* kbase = km + (size_t)(b * Ss + lo) * Hh + hi * 8;  // + key*Hh
  const ushort_t* vb0 = vt + ((size_t)(b * 64 + lo)) * Ss + hi * 8;  // + key col
  const ushort_t* vb1 = vt + ((size_t)(b * 64 + 32 + lo)) * Ss + hi * 8;

  // K prologue for iteration 0
  bf16x8 kA[4], kB[4];
#pragma unroll
  for (int c = 0; c < 4; ++c) {
    kA[c] = *reinterpret_cast<const bf16x8*>(kbase + (size_t)kvbeg * Hh + c * 16);
    kB[c] = *reinterpret_cast<const bf16x8*>(kbase + (size_t)(kvbeg + 32) * Hh + c * 16);
  }

#pragma unroll 2
  for (int it = 0; it < 8; ++it) {
    const int kvA = kvbeg + it * 64, kvB = kvA + 32;

    // ---- issue V_A + pen loads up front (needed ~400 cyc later) ----
    bf16x8 vfA00 = *reinterpret_cast<const bf16x8*>(vb0 + kvA);
    bf16x8 vfA10 = *reinterpret_cast<const bf16x8*>(vb0 + kvA + 16);
    bf16x8 vfA01 = *reinterpret_cast<const bf16x8*>(vb1 + kvA);
    bf16x8 vfA11 = *reinterpret_cast<const bf16x8*>(vb1 + kvA + 16);
    f32x4 pvA[4], pvB[4];
#pragma unroll
    for (int j = 0; j < 4; ++j) {
      pvA[j] = *reinterpret_cast<const f32x4*>(psel + kvA + j * 8 + hi * 4);
      pvB[j] = *reinterpret_cast<const f32x4*>(psel + kvB + j * 8 + hi * 4);
    }

    // ---- QK for both subtiles back-to-back (MFMA pipe stays fed) ----
    f32x16 scA = mfma32(kA[0], qf[0], z16);
    scA = mfma32(kA[1], qf[1], scA);
    scA = mfma32(kA[2], qf[2], scA);
    scA = mfma32(kA[3], qf[3], scA);
    f32x16 scB = mfma32(kB[0], qf[0], z16);
    scB = mfma32(kB[1], qf[1], scB);
    scB = mfma32(kB[2], qf[2], scB);
    scB = mfma32(kB[3], qf[3], scB);

    // ---- prefetch next iteration's K (wraps to kvbeg on last iter; unused) ----
    const int kvn = (it < 7) ? (kvA + 64) : kvbeg;
    bf16x8 knA[4], knB[4];
#pragma unroll
    for (int c = 0; c < 4; ++c) {
      knA[c] = *reinterpret_cast<const bf16x8*>(kbase + (size_t)kvn * Hh + c * 16);
      knB[c] = *reinterpret_cast<const bf16x8*>(kbase + (size_t)(kvn + 32) * Hh + c * 16);
    }

    // ---- softmax A (VALU; overlaps QK_B on MFMA pipe) ----
    if (kvA == q0) {
#pragma unroll
      for (int r = 0; r < 16; ++r) {
        int kr = (r & 3) + 8 * (r >> 2) + 4 * hi;
        scA[r] += pvA[r >> 2][r & 3] + ((kr > lo) ? negq : 0.f);
      }
    } else {
      float addt = (kvA > q0) ? negq : 0.f;
#pragma unroll
      for (int r = 0; r < 16; ++r) scA[r] += pvA[r >> 2][r & 3] + addt;
    }
    float pA[16], tsA = 0.f;
#pragma unroll
    for (int r = 0; r < 16; ++r) {
      pA[r] = __builtin_amdgcn_exp2f(scA[r]);
      tsA += pA[r];
    }
    ll += tsA;  // lane-local; cross-half sum hoisted out of loop
    unsigned xa0 = cvtpk(pA[0], pA[1]), ya0 = cvtpk(pA[2], pA[3]);
    unsigned za0 = cvtpk(pA[4], pA[5]), wa0 = cvtpk(pA[6], pA[7]);
    swap32(xa0, za0);
    swap32(ya0, wa0);
    unsigned xa1 = cvtpk(pA[8], pA[9]), ya1 = cvtpk(pA[10], pA[11]);
    unsigned za1 = cvtpk(pA[12], pA[13]), wa1 = cvtpk(pA[14], pA[15]);
    swap32(xa1, za1);
    swap32(ya1, wa1);
    bf16x8 paA0 = __builtin_bit_cast(bf16x8, u32x4{xa0, ya0, za0, wa0});
    bf16x8 paA1 = __builtin_bit_cast(bf16x8, u32x4{xa1, ya1, za1, wa1});

    // ---- V_B loads (hide under PV_A + softmax B) ----
    bf16x8 vfB00 = *reinterpret_cast<const bf16x8*>(vb0 + kvB);
    bf16x8 vfB10 = *reinterpret_cast<const bf16x8*>(vb0 + kvB + 16);
    bf16x8 vfB01 = *reinterpret_cast<const bf16x8*>(vb1 + kvB);
    bf16x8 vfB11 = *reinterpret_cast<const bf16x8*>(vb1 + kvB + 16);

    // ---- PV_A ----
    o0 = mfma32(paA0, vfA00, o0);
    o0 = mfma32(paA1, vfA10, o0);
    o1 = mfma32(paA0, vfA01, o1);
    o1 = mfma32(paA1, vfA11, o1);

    // ---- softmax B (VALU; overlaps PV_A on MFMA pipe) ----
    if (kvB == q0) {
#pragma unroll
      for (int r = 0; r < 16; ++r) {
        int kr = (r & 3) + 8 * (r >> 2) + 4 * hi;
        scB[r] += pvB[r >> 2][r & 3] + ((kr > lo) ? negq : 0.f);
      }
    } else {
      float addt = (kvB > q0) ? negq : 0.f;
#pragma unroll
      for (int r = 0; r < 16; ++r) scB[r] += pvB[r >> 2][r & 3] + addt;
    }
    float pB[16], tsB = 0.f;
#pragma unroll
    for (int r = 0; r < 16; ++r) {
      pB[r] = __builtin_amdgcn_exp2f(scB[r]);
      tsB += pB[r];
    }
    ll += tsB;
    unsigned xb0 = cvtpk(pB[0], pB[1]), yb0 = cvtpk(pB[2], pB[3]);
    unsigned zb0 = cvtpk(pB[4], pB[5]), wb0 = cvtpk(pB[6], pB[7]);
    swap32(xb0, zb0);
    swap32(yb0, wb0);
    unsigned xb1 = cvtpk(pB[8], pB[9]), yb1 = cvtpk(pB[10], pB[11]);
    unsigned zb1 = cvtpk(pB[12], pB[13]), wb1 = cvtpk(pB[14], pB[15]);
    swap32(xb1, zb1);
    swap32(yb1, wb1);
    bf16x8 paB0 = __builtin_bit_cast(bf16x8, u32x4{xb0, yb0, zb0, wb0});
    bf16x8 paB1 = __builtin_bit_cast(bf16x8, u32x4{xb1, yb1, zb1, wb1});

    // ---- PV_B ----
    o0 = mfma32(paB0, vfB00, o0);
    o0 = mfma32(paB1, vfB10, o0);
    o1 = mfma32(paB0, vfB01, o1);
    o1 = mfma32(paB1, vfB11, o1);

    // ---- rotate prefetched K ----
#pragma unroll
    for (int c = 0; c < 4; ++c) {
      kA[c] = knA[c];
      kB[c] = knB[c];
    }
  }

  ll += __shfl_xor(ll, 32);  // single cross-half reduce for the whole KV range

  // ---- stash partials ----
#pragma unroll
  for (int r = 0; r < 16; ++r) {
    int qrow = (r & 3) + 8 * (r >> 2) + 4 * hi;
    obuf[w][qrow][lo] = o0[r];
    obuf[w][qrow][32 + lo] = o1[r];
  }
  if (hi == 0) lls[w][lo] = ll;
  __syncthreads();

  // ---- combine 4 KV-split partials: thread -> (qr = t>>3, 8 d-cols) ----
  int qr = t >> 3, dg = t & 7;
  float lg = 0.f;
#pragma unroll
  for (int ww = 0; ww < 4; ++ww) lg += lls[ww][qr];
  float a8[8] = {0.f, 0.f, 0.f, 0.f, 0.f, 0.f, 0.f, 0.f};
#pragma unroll
  for (int ww = 0; ww < 4; ++ww) {
    float4 c0 = *reinterpret_cast<const float4*>(&obuf[ww][qr][dg * 8]);
    float4 c1 = *reinterpret_cast<const float4*>(&obuf[ww][qr][dg * 8 + 4]);
    a8[0] += c0.x; a8[1] += c0.y; a8[2] += c0.z; a8[3] += c0.w;
    a8[4] += c1.x; a8[5] += c1.y; a8[6] += c1.z; a8[7] += c1.w;
  }
  float inv = 1.f / lg;
  float4 r0 = {a8[0] * inv, a8[1] * inv, a8[2] * inv, a8[3] * inv};
  float4 r1 = {a8[4] * inv, a8[5] * inv, a8[6] * inv, a8[7] * inv};
  float* op = out + ((size_t)(b * Ss + q0 + qr)) * Hh + dg * 8;
  *reinterpret_cast<float4*>(op) = r0;
  *reinterpret_cast<float4*>(op + 4) = r1;
}

extern "C" void kernel_launch(void* const* d_in, const int* in_sizes, int n_in,
                              void* d_out, int out_size, void* d_ws, size_t ws_size,
                              hipStream_t stream) {
  const float* hs = (const float*)d_in[0];
  const int* am = (const int*)d_in[1];
  const float* Wq = (const float*)d_in[2];
  const float* bq = (const float*)d_in[3];
  const float* Wk = (const float*)d_in[4];
  const float* bk = (const float*)d_in[5];
  const float* Wv = (const float*)d_in[6];
  const float* bv = (const float*)d_in[7];
  float* out = (float*)d_out;

  char* ws = (char*)d_ws;
  ushort_t* qsp = (ushort_t*)(ws + 0);                  // 2 MB: [B*S][64] bf16, scaled
  ushort_t* kp = (ushort_t*)(ws + (2u << 20));          // 2 MB: [B*S][64] bf16
  ushort_t* vtp = (ushort_t*)(ws + (4u << 20));         // 2 MB: [B][64][S] bf16 (V^T)
  ushort_t* wtp = (ushort_t*)(ws + (6u << 20));         // 384 KB: [3][64][1024] bf16 (W^T)
  float* penp = (float*)(ws + (6u << 20) + (512u << 10));  // 128 KB: [B][2][S] f32

  k_wtrans<<<dim3(16, 3), 256, 0, stream>>>(Wq, Wk, Wv, wtp);
  k_proj<<<dim3(256), 512, 0, stream>>>(hs, bq, bk, bv, wtp, am, qsp, kp, vtp, penp);
  k_attn<<<dim3(512), 256, 0, stream>>>(qsp, kp, vtp, am, penp, out);
}

// Round 10
// 55.266 us; speedup vs baseline: 1.5997x; 1.2894x over previous
//
#include <hip/hip_runtime.h>

typedef float f32x4 __attribute__((ext_vector_type(4)));
typedef float f32x16 __attribute__((ext_vector_type(16)));
typedef unsigned int u32x4 __attribute__((ext_vector_type(4)));
typedef __bf16 bf16x8 __attribute__((ext_vector_type(8)));
typedef unsigned short ushort_t;

#define NEG2 (-144269.5f)   /* -1e5 * log2(e) */
#define SCLQ (0.18033688f)  /* 0.125 * log2(e) */

constexpr int Ss = 2048, Ee = 1024, Hh = 64;

static __device__ __forceinline__ ushort_t f2bfu(float f) {
  return __builtin_bit_cast(ushort_t, (__bf16)f);
}
static __device__ __forceinline__ f32x4 mfma16(bf16x8 a, bf16x8 b, f32x4 c) {
  return __builtin_amdgcn_mfma_f32_16x16x32_bf16(a, b, c, 0, 0, 0);
}
static __device__ __forceinline__ f32x16 mfma32(bf16x8 a, bf16x8 b, f32x16 c) {
  return __builtin_amdgcn_mfma_f32_32x32x16_bf16(a, b, c, 0, 0, 0);
}
static __device__ __forceinline__ unsigned cvtpk(float a, float b) {
  unsigned r;
  asm("v_cvt_pk_bf16_f32 %0, %1, %2" : "=v"(r) : "v"(a), "v"(b));
  return r;
}
// NOTE: only call with a,b holding DIFFERENT values (R3 bug: identical values
// tie to one phys reg -> in-place self-swap).
static __device__ __forceinline__ void swap32(unsigned& a, unsigned& b) {
  asm("v_permlane32_swap_b32 %0, %1" : "+v"(a), "+v"(b));
}

// ---------------- weight transpose + bf16 convert: Wt[m][h][e] ----------------
__global__ __launch_bounds__(256) void k_wtrans(const float* __restrict__ Wq,
                                                const float* __restrict__ Wk,
                                                const float* __restrict__ Wv,
                                                ushort_t* __restrict__ Wt) {
  __shared__ float tile[64][65];
  const float* W = (blockIdx.y == 0) ? Wq : (blockIdx.y == 1 ? Wk : Wv);
  int kt = blockIdx.x, t = threadIdx.x;
  int r = t >> 2, cq = t & 3;
  const float* src = W + (kt * 64 + r) * Hh + cq * 16;
#pragma unroll
  for (int j = 0; j < 16; j += 4) {
    float4 v = *reinterpret_cast<const float4*>(src + j);
    tile[r][cq * 16 + j + 0] = v.x;
    tile[r][cq * 16 + j + 1] = v.y;
    tile[r][cq * 16 + j + 2] = v.z;
    tile[r][cq * 16 + j + 3] = v.w;
  }
  __syncthreads();
  int n = t >> 2, kq = t & 3;
  ushort_t ob[16];
#pragma unroll
  for (int j = 0; j < 16; ++j) ob[j] = f2bfu(tile[kq * 16 + j][n]);
  ushort_t* dst = Wt + ((size_t)blockIdx.y * 64 + n) * Ee + kt * 64 + kq * 16;
  reinterpret_cast<uint4*>(dst)[0] = reinterpret_cast<uint4*>(ob)[0];
  reinterpret_cast<uint4*>(dst)[1] = reinterpret_cast<uint4*>(ob)[1];
}

// ---------------- fused QKV projection: LDS-staged, double-buffered ----------------
// (unchanged from R6 — proven)
__global__ __launch_bounds__(512, 4) void k_proj(const float* __restrict__ hs,
                                                 const float* __restrict__ bq,
                                                 const float* __restrict__ bk,
                                                 const float* __restrict__ bv,
                                                 const ushort_t* __restrict__ Wt,
                                                 const int* __restrict__ am,
                                                 ushort_t* __restrict__ q,
                                                 ushort_t* __restrict__ k,
                                                 ushort_t* __restrict__ vt,
                                                 float* __restrict__ pen) {
  __shared__ __align__(16) ushort_t bufA[2][64][72];   // 18 KB
  __shared__ __align__(16) ushort_t bufW[2][192][72];  // 54 KB

  int t = threadIdx.x, w = t >> 6, l = t & 63, g = l >> 4, c = l & 15;
  int wm = w >> 1, wn = w & 1;
  int row0 = blockIdx.x * 64;

  int ar = t >> 3, ach = t & 7;
  const float* agp = hs + (size_t)(row0 + ar) * Ee + ach * 8;
  const ushort_t* wgp = Wt + (size_t)(t >> 3) * Ee + (t & 7) * 8;

  f32x4 acc[6];
#pragma unroll
  for (int nt = 0; nt < 6; ++nt) acc[nt] = f32x4{0.f, 0.f, 0.f, 0.f};

  float4 aR0, aR1;
  u32x4 wR[3];

  auto LOAD = [&](int kk) {
    aR0 = *reinterpret_cast<const float4*>(agp + kk);
    aR1 = *reinterpret_cast<const float4*>(agp + kk + 4);
#pragma unroll
    for (int j = 0; j < 3; ++j)
      wR[j] = *reinterpret_cast<const u32x4*>(wgp + (size_t)j * 64 * Ee + kk);
  };
  auto WRITE = [&](int buf) {
    bf16x8 av;
    av[0] = (__bf16)aR0.x; av[1] = (__bf16)aR0.y; av[2] = (__bf16)aR0.z; av[3] = (__bf16)aR0.w;
    av[4] = (__bf16)aR1.x; av[5] = (__bf16)aR1.y; av[6] = (__bf16)aR1.z; av[7] = (__bf16)aR1.w;
    *reinterpret_cast<bf16x8*>(&bufA[buf][ar][ach * 8]) = av;
#pragma unroll
    for (int j = 0; j < 3; ++j)
      *reinterpret_cast<u32x4*>(&bufW[buf][(t >> 3) + j * 64][(t & 7) * 8]) = wR[j];
  };
  auto COMPUTE = [&](int buf) {
    const ushort_t* Ab = &bufA[buf][wm * 16 + c][0];
    bf16x8 af0 = *reinterpret_cast<const bf16x8*>(Ab + g * 8);
    bf16x8 af1 = *reinterpret_cast<const bf16x8*>(Ab + 32 + g * 8);
#pragma unroll
    for (int nt = 0; nt < 6; ++nt) {
      const ushort_t* Wb = &bufW[buf][wn * 96 + nt * 16 + c][0];
      bf16x8 b0 = *reinterpret_cast<const bf16x8*>(Wb + g * 8);
      bf16x8 b1 = *reinterpret_cast<const bf16x8*>(Wb + 32 + g * 8);
      acc[nt] = mfma16(af0, b0, acc[nt]);
      acc[nt] = mfma16(af1, b1, acc[nt]);
    }
  };

  LOAD(0);
  WRITE(0);
  __syncthreads();

  int cur = 0;
  for (int s = 0; s < 16; ++s) {
    if (s < 15) LOAD((s + 1) * 64);
    COMPUTE(cur);
    if (s < 15) {
      __syncthreads();
      WRITE(cur ^ 1);
      __syncthreads();
      cur ^= 1;
    }
  }

#pragma unroll
  for (int nt = 0; nt < 6; ++nt) {
    int T = wn * 6 + nt;
    int m = T >> 2;
    int h = (T & 3) * 16 + c;
    const float* bias = (m == 0) ? bq : ((m == 1) ? bk : bv);
    float bb = bias[h];
#pragma unroll
    for (int i = 0; i < 4; ++i) {
      int row = row0 + wm * 16 + g * 4 + i;
      float val = acc[nt][i] + bb;
      if (m == 0) {
        q[(size_t)row * Hh + h] = f2bfu(val * SCLQ);
      } else if (m == 1) {
        k[(size_t)row * Hh + h] = f2bfu(val);
      } else {
        int bi = row >> 11, s2 = row & 2047;
        vt[((size_t)(bi * 64 + h)) * Ss + s2] = f2bfu(val);
      }
    }
  }

  if (t < 64) {
    int grow = row0 + t;
    int bi = grow >> 11, s2 = grow & 2047;
    int mv = am[grow];
    pen[((size_t)bi * 2 + 0) * Ss + s2] = mv ? 0.f : NEG2;
    pen[((size_t)bi * 2 + 1) * Ss + s2] = mv ? NEG2 : 0.f;
  }
}

// ---------------- fused masked flash attention: LDS-staged K/V, coalesced ----------------
// R6/R8/R9 all plateaued at ~43 µs: per-lane fragment loads (lane stride 128B for
// K, 4KB for V) touch 32 distinct cache lines per b128 instr -> TA-transaction +
// 4x L2-overfetch bound. Fix: stage K[128][64] + V^T[64][128] per 128-key tile
// into LDS via COALESCED loads (every line byte used), double-buffered; fragments
// then come from LDS with XOR swizzle byte^=(row&7)<<4 on write AND read (T2;
// else 128B/256B row stride = 32-way bank conflict).
// grid 512 (b = bid&7 batch-per-XCD), 256 thr / 4 waves; wave w takes keys
// [tile + w*32). Fixed m=0 softmax. obuf combine buffer ALIASES the staging LDS
// (after barrier) to keep LDS at 66 KB -> 2 blocks/CU.
__global__ __launch_bounds__(256, 2) void k_attn(const ushort_t* __restrict__ qs,
                                                 const ushort_t* __restrict__ km,
                                                 const ushort_t* __restrict__ vt,
                                                 const int* __restrict__ am,
                                                 const float* __restrict__ pen,
                                                 float* __restrict__ out) {
  // [0,16K) K buf0 | [16K,32K) K buf1 | [32K,48K) V buf0 | [48K,64K) V buf1
  __shared__ __align__(16) char smem[65536];
  __shared__ float lls[4][32];

  int t = threadIdx.x, w = t >> 6, l = t & 63, lo = l & 31, hi = l >> 5;
  int bid = blockIdx.x;
  int b = bid & 7, q0 = (bid >> 3) * 32;

  // Q B-frags (hoisted): lane holds Q[q0+lo][c*16 + hi*8 + j]
  const ushort_t* qp = qs + ((size_t)(b * Ss + q0 + lo)) * Hh + hi * 8;
  bf16x8 qf[4];
#pragma unroll
  for (int c = 0; c < 4; ++c) qf[c] = *reinterpret_cast<const bf16x8*>(qp + c * 16);

  int mq = am[b * Ss + q0 + lo];
  float negq = mq ? NEG2 : 0.f;
  const float* psel = pen + ((size_t)b * 2 + (mq ? 0 : 1)) * Ss;

  float ll = 0.f;
  f32x16 o0 = {0.f, 0.f, 0.f, 0.f, 0.f, 0.f, 0.f, 0.f, 0.f, 0.f, 0.f, 0.f, 0.f, 0.f, 0.f, 0.f};
  f32x16 o1 = o0;
  const f32x16 z16 = o0;

  // ---- staging indices (coalesced: 8 consecutive threads cover one K row's 128B;
  //      16 consecutive threads cover one V row's 256B) ----
  const int r0 = t >> 3, c8 = t & 7;    // K: rows r0, r0+32, +64, +96; 16B chunk c8
  const int rv0 = t >> 4, cv = t & 15;  // V: rows rv0, +16, +32, +48; 16B chunk cv
  const ushort_t* kg = km + ((size_t)b * Ss + r0) * Hh + c8 * 8;
  const ushort_t* vg = vt + ((size_t)(b * 64 + rv0)) * Ss + cv * 8;
  const int swzK = (r0 & 7) << 4;
  const int swzV = (rv0 & 7) << 4;

  u32x4 kr0, kr1, kr2, kr3, vr0, vr1, vr2, vr3;  // named statics (rule #20)

  auto GLOAD = [&](int kv0) {
    kr0 = *reinterpret_cast<const u32x4*>(kg + (size_t)(kv0 + 0) * Hh);
    kr1 = *reinterpret_cast<const u32x4*>(kg + (size_t)(kv0 + 32) * Hh);
    kr2 = *reinterpret_cast<const u32x4*>(kg + (size_t)(kv0 + 64) * Hh);
    kr3 = *reinterpret_cast<const u32x4*>(kg + (size_t)(kv0 + 96) * Hh);
    vr0 = *reinterpret_cast<const u32x4*>(vg + (size_t)0 * Ss + kv0);
    vr1 = *reinterpret_cast<const u32x4*>(vg + (size_t)16 * Ss + kv0);
    vr2 = *reinterpret_cast<const u32x4*>(vg + (size_t)32 * Ss + kv0);
    vr3 = *reinterpret_cast<const u32x4*>(vg + (size_t)48 * Ss + kv0);
  };
  auto LWRITE = [&](int buf) {
    char* Kb = smem + buf * 16384;
    *reinterpret_cast<u32x4*>(Kb + ((((r0 + 0) * 128) + c8 * 16) ^ swzK)) = kr0;
    *reinterpret_cast<u32x4*>(Kb + ((((r0 + 32) * 128) + c8 * 16) ^ swzK)) = kr1;
    *reinterpret_cast<u32x4*>(Kb + ((((r0 + 64) * 128) + c8 * 16) ^ swzK)) = kr2;
    *reinterpret_cast<u32x4*>(Kb + ((((r0 + 96) * 128) + c8 * 16) ^ swzK)) = kr3;
    char* Vb = smem + 32768 + buf * 16384;
    *reinterpret_cast<u32x4*>(Vb + ((((rv0 + 0) * 256) + cv * 16) ^ swzV)) = vr0;
    *reinterpret_cast<u32x4*>(Vb + ((((rv0 + 16) * 256) + cv * 16) ^ swzV)) = vr1;
    *reinterpret_cast<u32x4*>(Vb + ((((rv0 + 32) * 256) + cv * 16) ^ swzV)) = vr2;
    *reinterpret_cast<u32x4*>(Vb + ((((rv0 + 48) * 256) + cv * 16) ^ swzV)) = vr3;
  };

  const int swz = (lo & 7) << 4;

  auto COMPUTE = [&](int buf, int it) {
    const char* Kb = smem + buf * 16384;
    const char* Vb = smem + 32768 + buf * 16384;
    const int kvw = it * 128 + w * 32;  // this wave's 32 keys (global index)
    const int krow = w * 32 + lo;       // row within K tile

    // K A-frags from LDS (swizzled)
    bf16x8 kf0 = *reinterpret_cast<const bf16x8*>(Kb + ((krow * 128 + 0 + hi * 16) ^ swz));
    bf16x8 kf1 = *reinterpret_cast<const bf16x8*>(Kb + ((krow * 128 + 32 + hi * 16) ^ swz));
    bf16x8 kf2 = *reinterpret_cast<const bf16x8*>(Kb + ((krow * 128 + 64 + hi * 16) ^ swz));
    bf16x8 kf3 = *reinterpret_cast<const bf16x8*>(Kb + ((krow * 128 + 96 + hi * 16) ^ swz));
    // V B-frags from LDS (rows = d, cols = local keys w*32..+32)
    bf16x8 vf00 = *reinterpret_cast<const bf16x8*>(Vb + ((lo * 256 + w * 64 + hi * 16) ^ swz));
    bf16x8 vf10 = *reinterpret_cast<const bf16x8*>(Vb + ((lo * 256 + w * 64 + hi * 16 + 32) ^ swz));
    bf16x8 vf01 = *reinterpret_cast<const bf16x8*>(Vb + (((lo + 32) * 256 + w * 64 + hi * 16) ^ swz));
    bf16x8 vf11 = *reinterpret_cast<const bf16x8*>(Vb + (((lo + 32) * 256 + w * 64 + hi * 16 + 32) ^ swz));

    // penalty vectors (global; lanes broadcast within half-wave -> 2 lines/instr)
    f32x4 pv[4];
#pragma unroll
    for (int j = 0; j < 4; ++j)
      pv[j] = *reinterpret_cast<const f32x4*>(psel + kvw + j * 8 + hi * 4);

    // ---- scores: D[key][q], key = (r&3)+8*(r>>2)+4*hi, q = lo ----
    f32x16 sc = mfma32(kf0, qf[0], z16);
    sc = mfma32(kf1, qf[1], sc);
    sc = mfma32(kf2, qf[2], sc);
    sc = mfma32(kf3, qf[3], sc);

    if (kvw == q0) {  // straddle tile: per-reg causal
#pragma unroll
      for (int r = 0; r < 16; ++r) {
        int kr = (r & 3) + 8 * (r >> 2) + 4 * hi;
        sc[r] += pv[r >> 2][r & 3] + ((kr > lo) ? negq : 0.f);
      }
    } else {
      float addt = (kvw > q0) ? negq : 0.f;
#pragma unroll
      for (int r = 0; r < 16; ++r) sc[r] += pv[r >> 2][r & 3] + addt;
    }

    // ---- p = exp2(sc), row sum (fixed m = 0; cross-half reduce hoisted) ----
    float p[16], ts = 0.f;
#pragma unroll
    for (int r = 0; r < 16; ++r) {
      p[r] = __builtin_amdgcn_exp2f(sc[r]);
      ts += p[r];
    }
    ll += ts;

    // ---- P -> PV A-frags: 8 cvt_pk + 4 permlane32_swap (distinct values: safe) ----
    unsigned x0 = cvtpk(p[0], p[1]), y0 = cvtpk(p[2], p[3]);
    unsigned z0 = cvtpk(p[4], p[5]), w0 = cvtpk(p[6], p[7]);
    swap32(x0, z0);
    swap32(y0, w0);
    unsigned x1 = cvtpk(p[8], p[9]), y1 = cvtpk(p[10], p[11]);
    unsigned z1 = cvtpk(p[12], p[13]), w1 = cvtpk(p[14], p[15]);
    swap32(x1, z1);
    swap32(y1, w1);
    bf16x8 pa0 = __builtin_bit_cast(bf16x8, u32x4{x0, y0, z0, w0});
    bf16x8 pa1 = __builtin_bit_cast(bf16x8, u32x4{x1, y1, z1, w1});

    // ---- PV: D[q][d] ----
    o0 = mfma32(pa0, vf00, o0);
    o0 = mfma32(pa1, vf10, o0);
    o1 = mfma32(pa0, vf01, o1);
    o1 = mfma32(pa1, vf11, o1);
  };

  // ---- double-buffered tile loop (R6-proj-proven barrier pattern) ----
  GLOAD(0);
  LWRITE(0);
  __syncthreads();
  int cur = 0;
  for (int it = 0; it < 16; ++it) {
    if (it < 15) GLOAD((it + 1) * 128);
    COMPUTE(cur, it);
    if (it < 15) {
      __syncthreads();
      LWRITE(cur ^ 1);
      __syncthreads();
      cur ^= 1;
    }
  }

  ll += __shfl_xor(ll, 32);  // single cross-half reduce for the whole KV range

  // ---- combine: obuf ALIASES staging LDS (safe after barrier) ----
  __syncthreads();
  float (*obuf)[32][68] = reinterpret_cast<float(*)[32][68]>(smem);
#pragma unroll
  for (int r = 0; r < 16; ++r) {
    int qrow = (r & 3) + 8 * (r >> 2) + 4 * hi;
    obuf[w][qrow][lo] = o0[r];
    obuf[w][qrow][32 + lo] = o1[r];
  }
  if (hi == 0) lls[w][lo] = ll;
  __syncthreads();

  int qr = t >> 3, dg = t & 7;
  float lg = 0.f;
#pragma unroll
  for (int ww = 0; ww < 4; ++ww) lg += lls[ww][qr];
  float a8[8] = {0.f, 0.f, 0.f, 0.f, 0.f, 0.f, 0.f, 0.f};
#pragma unroll
  for (int ww = 0; ww < 4; ++ww) {
    float4 c0 = *reinterpret_cast<const float4*>(&obuf[ww][qr][dg * 8]);
    float4 c1 = *reinterpret_cast<const float4*>(&obuf[ww][qr][dg * 8 + 4]);
    a8[0] += c0.x; a8[1] += c0.y; a8[2] += c0.z; a8[3] += c0.w;
    a8[4] += c1.x; a8[5] += c1.y; a8[6] += c1.z; a8[7] += c1.w;
  }
  float inv = 1.f / lg;
  float4 r0v = {a8[0] * inv, a8[1] * inv, a8[2] * inv, a8[3] * inv};
  float4 r1v = {a8[4] * inv, a8[5] * inv, a8[6] * inv, a8[7] * inv};
  float* op = out + ((size_t)(b * Ss + q0 + qr)) * Hh + dg * 8;
  *reinterpret_cast<float4*>(op) = r0v;
  *reinterpret_cast<float4*>(op + 4) = r1v;
}

extern "C" void kernel_launch(void* const* d_in, const int* in_sizes, int n_in,
                              void* d_out, int out_size, void* d_ws, size_t ws_size,
                              hipStream_t stream) {
  const float* hs = (const float*)d_in[0];
  const int* am = (const int*)d_in[1];
  const float* Wq = (const float*)d_in[2];
  const float* bq = (const float*)d_in[3];
  const float* Wk = (const float*)d_in[4];
  const float* bk = (const float*)d_in[5];
  const float* Wv = (const float*)d_in[6];
  const float* bv = (const float*)d_in[7];
  float* out = (float*)d_out;

  char* ws = (char*)d_ws;
  ushort_t* qsp = (ushort_t*)(ws + 0);                  // 2 MB: [B*S][64] bf16, scaled
  ushort_t* kp = (ushort_t*)(ws + (2u << 20));          // 2 MB: [B*S][64] bf16
  ushort_t* vtp = (ushort_t*)(ws + (4u << 20));         // 2 MB: [B][64][S] bf16 (V^T)
  ushort_t* wtp = (ushort_t*)(ws + (6u << 20));         // 384 KB: [3][64][1024] bf16 (W^T)
  float* penp = (float*)(ws + (6u << 20) + (512u << 10));  // 128 KB: [B][2][S] f32

  k_wtrans<<<dim3(16, 3), 256, 0, stream>>>(Wq, Wk, Wv, wtp);
  k_proj<<<dim3(256), 512, 0, stream>>>(hs, bq, bk, bv, wtp, am, qsp, kp, vtp, penp);
  k_attn<<<dim3(512), 256, 0, stream>>>(qsp, kp, vtp, am, penp, out);
}

// Round 11
// 54.463 us; speedup vs baseline: 1.6232x; 1.0147x over previous
//
#include <hip/hip_runtime.h>

typedef float f32x4 __attribute__((ext_vector_type(4)));
typedef float f32x16 __attribute__((ext_vector_type(16)));
typedef unsigned int u32x4 __attribute__((ext_vector_type(4)));
typedef __bf16 bf16x8 __attribute__((ext_vector_type(8)));
typedef unsigned short ushort_t;

#define NEG2 (-144269.5f)   /* -1e5 * log2(e) */
#define SCLQ (0.18033688f)  /* 0.125 * log2(e) */

constexpr int Ss = 2048, Ee = 1024, Hh = 64;

static __device__ __forceinline__ ushort_t f2bfu(float f) {
  return __builtin_bit_cast(ushort_t, (__bf16)f);
}
static __device__ __forceinline__ f32x4 mfma16(bf16x8 a, bf16x8 b, f32x4 c) {
  return __builtin_amdgcn_mfma_f32_16x16x32_bf16(a, b, c, 0, 0, 0);
}
static __device__ __forceinline__ f32x16 mfma32(bf16x8 a, bf16x8 b, f32x16 c) {
  return __builtin_amdgcn_mfma_f32_32x32x16_bf16(a, b, c, 0, 0, 0);
}
static __device__ __forceinline__ unsigned cvtpk(float a, float b) {
  unsigned r;
  asm("v_cvt_pk_bf16_f32 %0, %1, %2" : "=v"(r) : "v"(a), "v"(b));
  return r;
}
// NOTE: only call with a,b holding DIFFERENT values (R3 bug: identical values
// tie to one phys reg -> in-place self-swap).
static __device__ __forceinline__ void swap32(unsigned& a, unsigned& b) {
  asm("v_permlane32_swap_b32 %0, %1" : "+v"(a), "+v"(b));
}

// ---------------- weight transpose + bf16 convert: Wt[m][h][e] ----------------
__global__ __launch_bounds__(256) void k_wtrans(const float* __restrict__ Wq,
                                                const float* __restrict__ Wk,
                                                const float* __restrict__ Wv,
                                                ushort_t* __restrict__ Wt) {
  __shared__ float tile[64][65];
  const float* W = (blockIdx.y == 0) ? Wq : (blockIdx.y == 1 ? Wk : Wv);
  int kt = blockIdx.x, t = threadIdx.x;
  int r = t >> 2, cq = t & 3;
  const float* src = W + (kt * 64 + r) * Hh + cq * 16;
#pragma unroll
  for (int j = 0; j < 16; j += 4) {
    float4 v = *reinterpret_cast<const float4*>(src + j);
    tile[r][cq * 16 + j + 0] = v.x;
    tile[r][cq * 16 + j + 1] = v.y;
    tile[r][cq * 16 + j + 2] = v.z;
    tile[r][cq * 16 + j + 3] = v.w;
  }
  __syncthreads();
  int n = t >> 2, kq = t & 3;
  ushort_t ob[16];
#pragma unroll
  for (int j = 0; j < 16; ++j) ob[j] = f2bfu(tile[kq * 16 + j][n]);
  ushort_t* dst = Wt + ((size_t)blockIdx.y * 64 + n) * Ee + kt * 64 + kq * 16;
  reinterpret_cast<uint4*>(dst)[0] = reinterpret_cast<uint4*>(ob)[0];
  reinterpret_cast<uint4*>(dst)[1] = reinterpret_cast<uint4*>(ob)[1];
}

// ---------------- fused QKV projection: LDS-staged, double-buffered ----------------
// (unchanged from R6 — proven)
__global__ __launch_bounds__(512, 4) void k_proj(const float* __restrict__ hs,
                                                 const float* __restrict__ bq,
                                                 const float* __restrict__ bk,
                                                 const float* __restrict__ bv,
                                                 const ushort_t* __restrict__ Wt,
                                                 const int* __restrict__ am,
                                                 ushort_t* __restrict__ q,
                                                 ushort_t* __restrict__ k,
                                                 ushort_t* __restrict__ vt,
                                                 float* __restrict__ pen) {
  __shared__ __align__(16) ushort_t bufA[2][64][72];   // 18 KB
  __shared__ __align__(16) ushort_t bufW[2][192][72];  // 54 KB

  int t = threadIdx.x, w = t >> 6, l = t & 63, g = l >> 4, c = l & 15;
  int wm = w >> 1, wn = w & 1;
  int row0 = blockIdx.x * 64;

  int ar = t >> 3, ach = t & 7;
  const float* agp = hs + (size_t)(row0 + ar) * Ee + ach * 8;
  const ushort_t* wgp = Wt + (size_t)(t >> 3) * Ee + (t & 7) * 8;

  f32x4 acc[6];
#pragma unroll
  for (int nt = 0; nt < 6; ++nt) acc[nt] = f32x4{0.f, 0.f, 0.f, 0.f};

  float4 aR0, aR1;
  u32x4 wR[3];

  auto LOAD = [&](int kk) {
    aR0 = *reinterpret_cast<const float4*>(agp + kk);
    aR1 = *reinterpret_cast<const float4*>(agp + kk + 4);
#pragma unroll
    for (int j = 0; j < 3; ++j)
      wR[j] = *reinterpret_cast<const u32x4*>(wgp + (size_t)j * 64 * Ee + kk);
  };
  auto WRITE = [&](int buf) {
    bf16x8 av;
    av[0] = (__bf16)aR0.x; av[1] = (__bf16)aR0.y; av[2] = (__bf16)aR0.z; av[3] = (__bf16)aR0.w;
    av[4] = (__bf16)aR1.x; av[5] = (__bf16)aR1.y; av[6] = (__bf16)aR1.z; av[7] = (__bf16)aR1.w;
    *reinterpret_cast<bf16x8*>(&bufA[buf][ar][ach * 8]) = av;
#pragma unroll
    for (int j = 0; j < 3; ++j)
      *reinterpret_cast<u32x4*>(&bufW[buf][(t >> 3) + j * 64][(t & 7) * 8]) = wR[j];
  };
  auto COMPUTE = [&](int buf) {
    const ushort_t* Ab = &bufA[buf][wm * 16 + c][0];
    bf16x8 af0 = *reinterpret_cast<const bf16x8*>(Ab + g * 8);
    bf16x8 af1 = *reinterpret_cast<const bf16x8*>(Ab + 32 + g * 8);
#pragma unroll
    for (int nt = 0; nt < 6; ++nt) {
      const ushort_t* Wb = &bufW[buf][wn * 96 + nt * 16 + c][0];
      bf16x8 b0 = *reinterpret_cast<const bf16x8*>(Wb + g * 8);
      bf16x8 b1 = *reinterpret_cast<const bf16x8*>(Wb + 32 + g * 8);
      acc[nt] = mfma16(af0, b0, acc[nt]);
      acc[nt] = mfma16(af1, b1, acc[nt]);
    }
  };

  LOAD(0);
  WRITE(0);
  __syncthreads();

  int cur = 0;
  for (int s = 0; s < 16; ++s) {
    if (s < 15) LOAD((s + 1) * 64);
    COMPUTE(cur);
    if (s < 15) {
      __syncthreads();
      WRITE(cur ^ 1);
      __syncthreads();
      cur ^= 1;
    }
  }

#pragma unroll
  for (int nt = 0; nt < 6; ++nt) {
    int T = wn * 6 + nt;
    int m = T >> 2;
    int h = (T & 3) * 16 + c;
    const float* bias = (m == 0) ? bq : ((m == 1) ? bk : bv);
    float bb = bias[h];
#pragma unroll
    for (int i = 0; i < 4; ++i) {
      int row = row0 + wm * 16 + g * 4 + i;
      float val = acc[nt][i] + bb;
      if (m == 0) {
        q[(size_t)row * Hh + h] = f2bfu(val * SCLQ);
      } else if (m == 1) {
        k[(size_t)row * Hh + h] = f2bfu(val);
      } else {
        int bi = row >> 11, s2 = row & 2047;
        vt[((size_t)(bi * 64 + h)) * Ss + s2] = f2bfu(val);
      }
    }
  }

  if (t < 64) {
    int grow = row0 + t;
    int bi = grow >> 11, s2 = grow & 2047;
    int mv = am[grow];
    pen[((size_t)bi * 2 + 0) * Ss + s2] = mv ? 0.f : NEG2;
    pen[((size_t)bi * 2 + 1) * Ss + s2] = mv ? NEG2 : 0.f;
  }
}

// ---------------- fused masked flash attention: 64-q blocks, 1 barrier/iter ----------------
// grid 256 (b = bid&7 batch-per-XCD, qt = bid>>3, q0 = qt*64); 512 thr / 8 waves.
// Wave (wq = w>>2, wk = w&3): q-rows [q0+wq*32, +32), keys quarter wk of each
// 128-key tile. K[128][64] + V^T[64][128] staged per tile (32 KB) — now serves
// 64 queries (2x R10), halving staging + L2 K/V traffic. Single barrier per
// iteration: { bar; LWRITE(next); GLOAD(next+1); COMPUTE(cur) } — the one
// barrier covers both WAR (LWRITE overwrites buffer last read pre-barrier) and
// RAW (COMPUTE reads buffer LWRITten pre-barrier); GLOAD has a full iteration
// of compute to cover HBM/L2 latency. XOR swizzle byte^=(row&7)<<4 on write+read.
// Fixed m=0 softmax. obuf[4][64][64] f32 (64 KB) aliases staging LDS after barrier.
__global__ __launch_bounds__(512, 2) void k_attn(const ushort_t* __restrict__ qs,
                                                 const ushort_t* __restrict__ km,
                                                 const ushort_t* __restrict__ vt,
                                                 const int* __restrict__ am,
                                                 const float* __restrict__ pen,
                                                 float* __restrict__ out) {
  // [0,16K) K buf0 | [16K,32K) K buf1 | [32K,48K) V buf0 | [48K,64K) V buf1
  __shared__ __align__(16) char smem[65536];
  __shared__ float lls[4][64];

  int t = threadIdx.x, w = t >> 6, l = t & 63, lo = l & 31, hi = l >> 5;
  int wq = w >> 2, wk = w & 3;
  int bid = blockIdx.x;
  int b = bid & 7, q0 = (bid >> 3) * 64;
  int qg0 = q0 + wq * 32;  // this wave's 32 q-rows

  // Q B-frags (hoisted): lane holds Q[qg0+lo][c*16 + hi*8 + j]
  const ushort_t* qp = qs + ((size_t)(b * Ss + qg0 + lo)) * Hh + hi * 8;
  bf16x8 qf[4];
#pragma unroll
  for (int c = 0; c < 4; ++c) qf[c] = *reinterpret_cast<const bf16x8*>(qp + c * 16);

  int mq = am[b * Ss + qg0 + lo];
  float negq = mq ? NEG2 : 0.f;
  const float* psel = pen + ((size_t)b * 2 + (mq ? 0 : 1)) * Ss;

  float ll = 0.f;
  f32x16 o0 = {0.f, 0.f, 0.f, 0.f, 0.f, 0.f, 0.f, 0.f, 0.f, 0.f, 0.f, 0.f, 0.f, 0.f, 0.f, 0.f};
  f32x16 o1 = o0;
  const f32x16 z16 = o0;

  // ---- staging indices (512 threads, coalesced) ----
  const int r0 = t >> 3, c8 = t & 7;    // K: rows r0, r0+64; 16B chunk c8
  const int rv0 = t >> 4, cv = t & 15;  // V: rows rv0, rv0+32; 16B chunk cv
  const ushort_t* kg = km + ((size_t)b * Ss + r0) * Hh + c8 * 8;
  const ushort_t* vg = vt + ((size_t)(b * 64 + rv0)) * Ss + cv * 8;
  const int swzK = (r0 & 7) << 4;   // (r0+64)&7 == r0&7
  const int swzV = (rv0 & 7) << 4;  // (rv0+32)&7 == rv0&7

  u32x4 kr0, kr1, vr0, vr1;  // named statics (rule #20)

  auto GLOAD = [&](int kv0) {
    kr0 = *reinterpret_cast<const u32x4*>(kg + (size_t)(kv0 + 0) * Hh);
    kr1 = *reinterpret_cast<const u32x4*>(kg + (size_t)(kv0 + 64) * Hh);
    vr0 = *reinterpret_cast<const u32x4*>(vg + kv0);
    vr1 = *reinterpret_cast<const u32x4*>(vg + (size_t)32 * Ss + kv0);
  };
  auto LWRITE = [&](int buf) {
    char* Kb = smem + buf * 16384;
    *reinterpret_cast<u32x4*>(Kb + (((r0 + 0) * 128 + c8 * 16) ^ swzK)) = kr0;
    *reinterpret_cast<u32x4*>(Kb + (((r0 + 64) * 128 + c8 * 16) ^ swzK)) = kr1;
    char* Vb = smem + 32768 + buf * 16384;
    *reinterpret_cast<u32x4*>(Vb + (((rv0 + 0) * 256 + cv * 16) ^ swzV)) = vr0;
    *reinterpret_cast<u32x4*>(Vb + (((rv0 + 32) * 256 + cv * 16) ^ swzV)) = vr1;
  };

  const int swz = (lo & 7) << 4;

  auto COMPUTE = [&](int buf, int it) {
    const char* Kb = smem + buf * 16384;
    const char* Vb = smem + 32768 + buf * 16384;
    const int kvw = it * 128 + wk * 32;  // this wave's 32 keys (global index)
    const int krow = wk * 32 + lo;       // row within K tile

    bf16x8 kf0 = *reinterpret_cast<const bf16x8*>(Kb + ((krow * 128 + 0 + hi * 16) ^ swz));
    bf16x8 kf1 = *reinterpret_cast<const bf16x8*>(Kb + ((krow * 128 + 32 + hi * 16) ^ swz));
    bf16x8 kf2 = *reinterpret_cast<const bf16x8*>(Kb + ((krow * 128 + 64 + hi * 16) ^ swz));
    bf16x8 kf3 = *reinterpret_cast<const bf16x8*>(Kb + ((krow * 128 + 96 + hi * 16) ^ swz));
    bf16x8 vf00 = *reinterpret_cast<const bf16x8*>(Vb + ((lo * 256 + wk * 64 + hi * 16) ^ swz));
    bf16x8 vf10 = *reinterpret_cast<const bf16x8*>(Vb + ((lo * 256 + wk * 64 + hi * 16 + 32) ^ swz));
    bf16x8 vf01 = *reinterpret_cast<const bf16x8*>(Vb + (((lo + 32) * 256 + wk * 64 + hi * 16) ^ swz));
    bf16x8 vf11 = *reinterpret_cast<const bf16x8*>(Vb + (((lo + 32) * 256 + wk * 64 + hi * 16 + 32) ^ swz));

    f32x4 pv[4];
#pragma unroll
    for (int j = 0; j < 4; ++j)
      pv[j] = *reinterpret_cast<const f32x4*>(psel + kvw + j * 8 + hi * 4);

    // ---- scores: D[key][q], key = (r&3)+8*(r>>2)+4*hi, q = lo ----
    f32x16 sc = mfma32(kf0, qf[0], z16);
    sc = mfma32(kf1, qf[1], sc);
    sc = mfma32(kf2, qf[2], sc);
    sc = mfma32(kf3, qf[3], sc);

    if (kvw == qg0) {  // straddle tile: per-reg causal
#pragma unroll
      for (int r = 0; r < 16; ++r) {
        int kr = (r & 3) + 8 * (r >> 2) + 4 * hi;
        sc[r] += pv[r >> 2][r & 3] + ((kr > lo) ? negq : 0.f);
      }
    } else {
      float addt = (kvw > qg0) ? negq : 0.f;
#pragma unroll
      for (int r = 0; r < 16; ++r) sc[r] += pv[r >> 2][r & 3] + addt;
    }

    // ---- p = exp2(sc), row sum (fixed m = 0; cross-half reduce hoisted) ----
    float p[16], ts = 0.f;
#pragma unroll
    for (int r = 0; r < 16; ++r) {
      p[r] = __builtin_amdgcn_exp2f(sc[r]);
      ts += p[r];
    }
    ll += ts;

    // ---- P -> PV A-frags: 8 cvt_pk + 4 permlane32_swap (distinct values: safe) ----
    unsigned x0 = cvtpk(p[0], p[1]), y0 = cvtpk(p[2], p[3]);
    unsigned z0 = cvtpk(p[4], p[5]), w0 = cvtpk(p[6], p[7]);
    swap32(x0, z0);
    swap32(y0, w0);
    unsigned x1 = cvtpk(p[8], p[9]), y1 = cvtpk(p[10], p[11]);
    unsigned z1 = cvtpk(p[12], p[13]), w1 = cvtpk(p[14], p[15]);
    swap32(x1, z1);
    swap32(y1, w1);
    bf16x8 pa0 = __builtin_bit_cast(bf16x8, u32x4{x0, y0, z0, w0});
    bf16x8 pa1 = __builtin_bit_cast(bf16x8, u32x4{x1, y1, z1, w1});

    // ---- PV: D[q][d] ----
    o0 = mfma32(pa0, vf00, o0);
    o0 = mfma32(pa1, vf10, o0);
    o1 = mfma32(pa0, vf01, o1);
    o1 = mfma32(pa1, vf11, o1);
  };

  // ---- single-barrier double-buffered tile loop ----
  GLOAD(0);
  LWRITE(0);
  GLOAD(128);
  int cur = 0;
  for (int it = 0; it < 16; ++it) {
    __syncthreads();                       // RAW: tile it staged; WAR: buf cur^1 free
    if (it < 15) LWRITE(cur ^ 1);          // write tile it+1 (regs from GLOAD)
    if (it < 14) GLOAD((it + 2) * 128);    // issue loads for tile it+2
    COMPUTE(cur, it);
    cur ^= 1;
  }

  ll += __shfl_xor(ll, 32);  // single cross-half reduce for the whole KV range

  // ---- combine: obuf[4][64][64] ALIASES staging LDS (safe after barrier) ----
  __syncthreads();
  float (*obuf)[64][64] = reinterpret_cast<float(*)[64][64]>(smem);
#pragma unroll
  for (int r = 0; r < 16; ++r) {
    int qrow = (r & 3) + 8 * (r >> 2) + 4 * hi;
    obuf[wk][wq * 32 + qrow][lo] = o0[r];
    obuf[wk][wq * 32 + qrow][32 + lo] = o1[r];
  }
  if (hi == 0) lls[wk][wq * 32 + lo] = ll;
  __syncthreads();

  int qr = t >> 3, dg = t & 7;
  float lg = lls[0][qr] + lls[1][qr] + lls[2][qr] + lls[3][qr];
  float a8[8] = {0.f, 0.f, 0.f, 0.f, 0.f, 0.f, 0.f, 0.f};
#pragma unroll
  for (int ww = 0; ww < 4; ++ww) {
    float4 c0 = *reinterpret_cast<const float4*>(&obuf[ww][qr][dg * 8]);
    float4 c1 = *reinterpret_cast<const float4*>(&obuf[ww][qr][dg * 8 + 4]);
    a8[0] += c0.x; a8[1] += c0.y; a8[2] += c0.z; a8[3] += c0.w;
    a8[4] += c1.x; a8[5] += c1.y; a8[6] += c1.z; a8[7] += c1.w;
  }
  float inv = 1.f / lg;
  float4 r0v = {a8[0] * inv, a8[1] * inv, a8[2] * inv, a8[3] * inv};
  float4 r1v = {a8[4] * inv, a8[5] * inv, a8[6] * inv, a8[7] * inv};
  float* op = out + ((size_t)(b * Ss + q0 + qr)) * Hh + dg * 8;
  *reinterpret_cast<float4*>(op) = r0v;
  *reinterpret_cast<float4*>(op + 4) = r1v;
}

extern "C" void kernel_launch(void* const* d_in, const int* in_sizes, int n_in,
                              void* d_out, int out_size, void* d_ws, size_t ws_size,
                              hipStream_t stream) {
  const float* hs = (const float*)d_in[0];
  const int* am = (const int*)d_in[1];
  const float* Wq = (const float*)d_in[2];
  const float* bq = (const float*)d_in[3];
  const float* Wk = (const float*)d_in[4];
  const float* bk = (const float*)d_in[5];
  const float* Wv = (const float*)d_in[6];
  const float* bv = (const float*)d_in[7];
  float* out = (float*)d_out;

  char* ws = (char*)d_ws;
  ushort_t* qsp = (ushort_t*)(ws + 0);                  // 2 MB: [B*S][64] bf16, scaled
  ushort_t* kp = (ushort_t*)(ws + (2u << 20));          // 2 MB: [B*S][64] bf16
  ushort_t* vtp = (ushort_t*)(ws + (4u << 20));         // 2 MB: [B][64][S] bf16 (V^T)
  ushort_t* wtp = (ushort_t*)(ws + (6u << 20));         // 384 KB: [3][64][1024] bf16 (W^T)
  float* penp = (float*)(ws + (6u << 20) + (512u << 10));  // 128 KB: [B][2][S] f32

  k_wtrans<<<dim3(16, 3), 256, 0, stream>>>(Wq, Wk, Wv, wtp);
  k_proj<<<dim3(256), 512, 0, stream>>>(hs, bq, bk, bv, wtp, am, qsp, kp, vtp, penp);
  k_attn<<<dim3(256), 512, 0, stream>>>(qsp, kp, vtp, am, penp, out);
}